// Round 4
// baseline (617.815 us; speedup 1.0000x reference)
//
#include <hip/hip_runtime.h>

typedef _Float16 f16;
typedef f16 f16x8 __attribute__((ext_vector_type(8)));
typedef float f32x4 __attribute__((ext_vector_type(4)));

#define EPSBN 1e-3f

// ---------------- prep: fold BN into weights, transpose to [N][K] f16, cvt inputs ----------------
__global__ __launch_bounds__(256) void prep_kernel(
    const float* __restrict__ inputs,
    const float* __restrict__ att_w, const float* __restrict__ att_gamma,
    const float* __restrict__ att_beta, const float* __restrict__ att_mean,
    const float* __restrict__ att_var,
    const float* __restrict__ proj_w,
    const float* __restrict__ glu_w, const float* __restrict__ glu_gamma,
    const float* __restrict__ glu_beta, const float* __restrict__ glu_mean,
    const float* __restrict__ glu_var,
    const float* __restrict__ out_w,
    f16* __restrict__ inputs16,
    f16* __restrict__ watt, f16* __restrict__ wproj, f16* __restrict__ wglu,
    f16* __restrict__ wout, float* __restrict__ t_att, float* __restrict__ t_glu)
{
    int tid = blockIdx.x * blockDim.x + threadIdx.x;
    int nth = gridDim.x * blockDim.x;
    // inputs f32 -> f16, vectorized
    for (int i = tid; i < 65536 * 512 / 8; i += nth) {
        float4 u0 = ((const float4*)inputs)[i * 2];
        float4 u1 = ((const float4*)inputs)[i * 2 + 1];
        f16x8 h = {(f16)u0.x, (f16)u0.y, (f16)u0.z, (f16)u0.w,
                   (f16)u1.x, (f16)u1.y, (f16)u1.z, (f16)u1.w};
        ((f16x8*)inputs16)[i] = h;
    }
    // att_w [512][512] -> watt [n][k], BN scale folded
    for (int i = tid; i < 512 * 512; i += nth) {
        int n = i >> 9, k = i & 511;
        float s = att_gamma[n] * rsqrtf(att_var[n] + EPSBN);
        watt[i] = (f16)(att_w[k * 512 + n] * s);
    }
    // proj_w [512][256] -> wproj [n=256][k=512]
    for (int i = tid; i < 256 * 512; i += nth) {
        int n = i >> 9, k = i & 511;
        wproj[i] = (f16)(proj_w[k * 256 + n]);
    }
    // glu_w [4][256][512] -> wglu [g][n=512 interleaved val/gate][k=256]
    for (int i = tid; i < 4 * 512 * 256; i += nth) {
        int g = i >> 17, r = i & 131071;
        int n = r >> 8, k = r & 255;
        int c = (n & 1) ? 256 + (n >> 1) : (n >> 1);
        float s = glu_gamma[g * 512 + c] * rsqrtf(glu_var[g * 512 + c] + EPSBN);
        wglu[i] = (f16)(glu_w[g * 131072 + k * 512 + c] * s);
    }
    // out_w [256][128] -> wout [n=128][k=256]
    for (int i = tid; i < 128 * 256; i += nth) {
        int n = i >> 8, k = i & 255;
        wout[i] = (f16)(out_w[k * 128 + n]);
    }
    for (int n = tid; n < 512; n += nth) {
        float s = att_gamma[n] * rsqrtf(att_var[n] + EPSBN);
        t_att[n] = att_beta[n] - att_mean[n] * s;
    }
    for (int i = tid; i < 4 * 512; i += nth) {
        int g = i >> 9, n = i & 511;
        int c = (n & 1) ? 256 + (n >> 1) : (n >> 1);
        float s = glu_gamma[g * 512 + c] * rsqrtf(glu_var[g * 512 + c] + EPSBN);
        t_glu[i] = glu_beta[g * 512 + c] - glu_mean[g * 512 + c] * s;
    }
}

// ---------------- fused att GEMM + sparsemax ----------------
// 64 rows/block, 8 waves. Wave w computes z cols [w*64, w*64+64), K=512.
// A (inputs16) and B (watt, L2-resident) read directly from global.
// z -> padded LDS, then per-wave sparsemax on rows w*8..w*8+7.
__global__ __launch_bounds__(512) void att_sparsemax_kernel(
    const f16* __restrict__ in16, const f16* __restrict__ watt,
    const float* __restrict__ t_att, const float* __restrict__ priors,
    float* __restrict__ maskout, float* __restrict__ npout,
    f16* __restrict__ masked)
{
    __shared__ f16 Z[64 * 520];  // pad 8 f16 -> conflict-free row reads
    const int rBase = blockIdx.x * 64;
    const int tid = threadIdx.x;
    const int lane = tid & 63;
    const int w = tid >> 6;
    const int lr = lane & 15, lq = lane >> 4;

    f32x4 acc[4][4];
#pragma unroll
    for (int m = 0; m < 4; m++)
#pragma unroll
        for (int n = 0; n < 4; n++) acc[m][n] = (f32x4){0.f, 0.f, 0.f, 0.f};

    const f16* Ab = in16 + (size_t)rBase * 512;
    const f16* Bb = watt + (size_t)(w * 64) * 512;
#pragma unroll 4
    for (int k0 = 0; k0 < 512; k0 += 32) {
        f16x8 af[4], bf[4];
#pragma unroll
        for (int m = 0; m < 4; m++)
            af[m] = *(const f16x8*)(Ab + (size_t)(m * 16 + lr) * 512 + k0 + lq * 8);
#pragma unroll
        for (int n = 0; n < 4; n++)
            bf[n] = *(const f16x8*)(Bb + (size_t)(n * 16 + lr) * 512 + k0 + lq * 8);
#pragma unroll
        for (int m = 0; m < 4; m++)
#pragma unroll
            for (int n = 0; n < 4; n++)
                acc[m][n] = __builtin_amdgcn_mfma_f32_16x16x32_f16(af[m], bf[n], acc[m][n], 0, 0, 0);
    }

    // z (BN output, f16) into LDS; C frag: col=lr, row=lq*4+j
#pragma unroll
    for (int n = 0; n < 4; n++) {
        const int col = w * 64 + n * 16 + lr;
        const float t = t_att[col];
#pragma unroll
        for (int m = 0; m < 4; m++)
#pragma unroll
            for (int j = 0; j < 4; j++)
                Z[(m * 16 + lq * 4 + j) * 520 + col] = (f16)(acc[m][n][j] + t);
    }
    __syncthreads();

    // sparsemax: wave w handles rows w*8 .. w*8+7, one row per pass (64 lanes x 8 elems)
    for (int i = 0; i < 8; ++i) {
        const int row = w * 8 + i;
        const size_t gbase = (size_t)(rBase + row) * 512 + lane * 8;
        f16x8 zv = *(const f16x8*)&Z[row * 520 + lane * 8];
        float4 p0 = *(const float4*)(priors + gbase);
        float4 p1 = *(const float4*)(priors + gbase + 4);
        float pr[8] = {p0.x, p0.y, p0.z, p0.w, p1.x, p1.y, p1.z, p1.w};
        float z[8];
#pragma unroll
        for (int j = 0; j < 8; j++) z[j] = (float)zv[j] * pr[j];
        float mx = z[0];
#pragma unroll
        for (int j = 1; j < 8; j++) mx = fmaxf(mx, z[j]);
#pragma unroll
        for (int d = 1; d < 64; d <<= 1) mx = fmaxf(mx, __shfl_xor(mx, d, 64));
        float lo = mx - 1.f, hi = mx;
        for (int it = 0; it < 16; ++it) {
            float tau = 0.5f * (lo + hi);
            float s = 0.f;
#pragma unroll
            for (int j = 0; j < 8; j++) s += fmaxf(z[j] - tau, 0.f);
#pragma unroll
            for (int d = 1; d < 64; d <<= 1) s += __shfl_xor(s, d, 64);
            if (s >= 1.f) lo = tau; else hi = tau;
        }
        float cnt = 0.f, sm = 0.f;
#pragma unroll
        for (int j = 0; j < 8; j++) {
            if (z[j] > lo) { cnt += 1.f; sm += z[j]; }
        }
#pragma unroll
        for (int d = 1; d < 64; d <<= 1) {
            cnt += __shfl_xor(cnt, d, 64);
            sm += __shfl_xor(sm, d, 64);
        }
        const float tau = (sm - 1.f) / cnt;
        f16x8 xv = *(const f16x8*)(in16 + gbase);
        float mk[8];
#pragma unroll
        for (int j = 0; j < 8; j++) mk[j] = fmaxf(z[j] - tau, 0.f);
        float4 m0 = {mk[0], mk[1], mk[2], mk[3]}, m1 = {mk[4], mk[5], mk[6], mk[7]};
        *(float4*)(maskout + gbase) = m0;
        *(float4*)(maskout + gbase + 4) = m1;
        float4 n0 = {pr[0] * (1.f - mk[0]), pr[1] * (1.f - mk[1]),
                     pr[2] * (1.f - mk[2]), pr[3] * (1.f - mk[3])};
        float4 n1 = {pr[4] * (1.f - mk[4]), pr[5] * (1.f - mk[5]),
                     pr[6] * (1.f - mk[6]), pr[7] * (1.f - mk[7])};
        *(float4*)(npout + gbase) = n0;
        *(float4*)(npout + gbase + 4) = n1;
        f16x8 mm;
#pragma unroll
        for (int j = 0; j < 8; j++) mm[j] = (f16)(mk[j] * (float)xv[j]);
        *(f16x8*)(masked + gbase) = mm;
    }
}

// ---------------- fused feature chain: proj + 4x GLU + out ----------------
// 64 rows/block, 8 waves. x ping-pongs in LDS [64][264] f16 (pad 8).
// All weights read directly from global (L2-resident).
__global__ __launch_bounds__(512) void chain_kernel(
    const f16* __restrict__ masked, const f16* __restrict__ wproj,
    const float* __restrict__ proj_b, const f16* __restrict__ wglu,
    const float* __restrict__ t_glu, const f16* __restrict__ wout,
    const float* __restrict__ out_b, float* __restrict__ outp)
{
    __shared__ f16 X0[64 * 264];
    __shared__ f16 X1[64 * 264];
    const int rBase = blockIdx.x * 64;
    const int tid = threadIdx.x;
    const int lane = tid & 63;
    const int w = tid >> 6;
    const int lr = lane & 15, lq = lane >> 4;

    // ---- proj: C 64x256, wave cols [w*32, w*32+32), K=512 ----
    {
        f32x4 acc[4][2];
#pragma unroll
        for (int m = 0; m < 4; m++)
#pragma unroll
            for (int n = 0; n < 2; n++) acc[m][n] = (f32x4){0.f, 0.f, 0.f, 0.f};
        const f16* Ab = masked + (size_t)rBase * 512;
        const f16* Bb = wproj + (size_t)(w * 32) * 512;
#pragma unroll 4
        for (int k0 = 0; k0 < 512; k0 += 32) {
            f16x8 af[4], bf[2];
#pragma unroll
            for (int m = 0; m < 4; m++)
                af[m] = *(const f16x8*)(Ab + (size_t)(m * 16 + lr) * 512 + k0 + lq * 8);
#pragma unroll
            for (int n = 0; n < 2; n++)
                bf[n] = *(const f16x8*)(Bb + (size_t)(n * 16 + lr) * 512 + k0 + lq * 8);
#pragma unroll
            for (int m = 0; m < 4; m++)
#pragma unroll
                for (int n = 0; n < 2; n++)
                    acc[m][n] = __builtin_amdgcn_mfma_f32_16x16x32_f16(af[m], bf[n], acc[m][n], 0, 0, 0);
        }
#pragma unroll
        for (int n = 0; n < 2; n++) {
            const int col = w * 32 + n * 16 + lr;
            const float t = proj_b[col];
#pragma unroll
            for (int m = 0; m < 4; m++)
#pragma unroll
                for (int j = 0; j < 4; j++)
                    X0[(m * 16 + lq * 4 + j) * 264 + col] = (f16)(acc[m][n][j] + t);
        }
    }
    __syncthreads();

    // ---- 4 GLU blocks: C 64x512 (interleaved val/gate), wave cols [w*64, +64), K=256 ----
    f16* cur = X0;
    f16* nxt = X1;
#pragma unroll 1
    for (int g = 0; g < 4; ++g) {
        f32x4 acc[4][4];
#pragma unroll
        for (int m = 0; m < 4; m++)
#pragma unroll
            for (int n = 0; n < 4; n++) acc[m][n] = (f32x4){0.f, 0.f, 0.f, 0.f};
        const f16* Bb = wglu + (size_t)g * 131072 + (size_t)(w * 64) * 256;
#pragma unroll 2
        for (int k0 = 0; k0 < 256; k0 += 32) {
            f16x8 af[4], bf[4];
#pragma unroll
            for (int m = 0; m < 4; m++)
                af[m] = *(const f16x8*)&cur[(m * 16 + lr) * 264 + k0 + lq * 8];
#pragma unroll
            for (int n = 0; n < 4; n++)
                bf[n] = *(const f16x8*)(Bb + (size_t)(n * 16 + lr) * 256 + k0 + lq * 8);
#pragma unroll
            for (int m = 0; m < 4; m++)
#pragma unroll
                for (int n = 0; n < 4; n++)
                    acc[m][n] = __builtin_amdgcn_mfma_f32_16x16x32_f16(af[m], bf[n], acc[m][n], 0, 0, 0);
        }
#pragma unroll
        for (int n = 0; n < 4; n++) {
            const int col = w * 64 + n * 16 + lr;
            const float t = t_glu[g * 512 + col];
#pragma unroll
            for (int m = 0; m < 4; m++)
#pragma unroll
                for (int j = 0; j < 4; j++) {
                    float v = acc[m][n][j] + t;
                    float o = __shfl_xor(v, 1, 64);  // val<->gate (adjacent lanes)
                    if (!(lane & 1)) {
                        const int xi = col >> 1;
                        const int row = m * 16 + lq * 4 + j;
                        float xn = v * (1.f / (1.f + __expf(-o)));
                        nxt[row * 264 + xi] = (f16)(xn + (float)cur[row * 264 + xi]);
                    }
                }
        }
        __syncthreads();
        f16* tmp = cur; cur = nxt; nxt = tmp;
    }

    // ---- out: C 64x128, wave cols [w*16, w*16+16), K=256 ----
    {
        f32x4 acc[4];
#pragma unroll
        for (int m = 0; m < 4; m++) acc[m] = (f32x4){0.f, 0.f, 0.f, 0.f};
        const f16* Bb = wout + (size_t)(w * 16) * 256;
#pragma unroll 2
        for (int k0 = 0; k0 < 256; k0 += 32) {
            f16x8 af[4];
            f16x8 b0 = *(const f16x8*)(Bb + (size_t)lr * 256 + k0 + lq * 8);
#pragma unroll
            for (int m = 0; m < 4; m++)
                af[m] = *(const f16x8*)&cur[(m * 16 + lr) * 264 + k0 + lq * 8];
#pragma unroll
            for (int m = 0; m < 4; m++)
                acc[m] = __builtin_amdgcn_mfma_f32_16x16x32_f16(af[m], b0, acc[m], 0, 0, 0);
        }
        const int col = w * 16 + lr;
        const float t = out_b[col];
#pragma unroll
        for (int m = 0; m < 4; m++)
#pragma unroll
            for (int j = 0; j < 4; j++)
                outp[(size_t)(rBase + m * 16 + lq * 4 + j) * 128 + col] = acc[m][j] + t;
    }
}

extern "C" void kernel_launch(void* const* d_in, const int* in_sizes, int n_in,
                              void* d_out, int out_size, void* d_ws, size_t ws_size,
                              hipStream_t stream)
{
    const float* inputs    = (const float*)d_in[0];
    const float* priors    = (const float*)d_in[1];
    const float* att_w     = (const float*)d_in[2];
    const float* att_gamma = (const float*)d_in[3];
    const float* att_beta  = (const float*)d_in[4];
    const float* att_mean  = (const float*)d_in[5];
    const float* att_var   = (const float*)d_in[6];
    const float* proj_w    = (const float*)d_in[7];
    const float* proj_b    = (const float*)d_in[8];
    const float* glu_w     = (const float*)d_in[9];
    const float* glu_gamma = (const float*)d_in[10];
    const float* glu_beta  = (const float*)d_in[11];
    const float* glu_mean  = (const float*)d_in[12];
    const float* glu_var   = (const float*)d_in[13];
    const float* out_w     = (const float*)d_in[14];
    const float* out_b     = (const float*)d_in[15];

    char* ws = (char*)d_ws;
    f16*   watt     = (f16*)(ws + 0);          // 512*512 f16
    f16*   wproj    = (f16*)(ws + 524288);     // 256*512
    f16*   wglu     = (f16*)(ws + 786432);     // 4*512*256
    f16*   wout     = (f16*)(ws + 1835008);    // 128*256
    float* t_att    = (float*)(ws + 1900544);  // 512
    float* t_glu    = (float*)(ws + 1902592);  // 4*512
    f16*   inputs16 = (f16*)(ws + 2097152);    // 65536*512 f16 (64MB)
    f16*   maskedb  = (f16*)(ws + 69206016);   // 65536*512 f16

    float* outp  = (float*)d_out;
    float* maskp = outp + (size_t)65536 * 128;
    float* npp   = maskp + (size_t)65536 * 512;

    prep_kernel<<<2048, 256, 0, stream>>>(inputs, att_w, att_gamma, att_beta, att_mean,
                                          att_var, proj_w, glu_w, glu_gamma, glu_beta,
                                          glu_mean, glu_var, out_w, inputs16,
                                          watt, wproj, wglu, wout, t_att, t_glu);

    att_sparsemax_kernel<<<1024, 512, 0, stream>>>(
        inputs16, watt, t_att, priors, maskp, npp, maskedb);

    chain_kernel<<<1024, 512, 0, stream>>>(
        maskedb, wproj, proj_b, wglu, t_glu, wout, out_b, outp);
}

// Round 8
// 512.208 us; speedup vs baseline: 1.2062x; 1.2062x over previous
//
#include <hip/hip_runtime.h>

typedef _Float16 f16;
typedef f16 f16x8 __attribute__((ext_vector_type(8)));
typedef float f32x4 __attribute__((ext_vector_type(4)));

#define EPSBN 1e-3f

enum { EPI_PROJ = 1, EPI_GLU = 2, EPI_OUT = 3 };

// async global->LDS, 16B per lane; lds dest is wave-uniform base (+lane*16 by HW)
__device__ __forceinline__ void stage16(const f16* g, const f16* l) {
    __builtin_amdgcn_global_load_lds(
        (const __attribute__((address_space(1))) unsigned int*)g,
        (__attribute__((address_space(3))) unsigned int*)l,
        16, 0, 0);
}

// ---------------- prep: fold BN into weights, transpose to [N][K] f16, cvt inputs ----------------
__global__ __launch_bounds__(256) void prep_kernel(
    const float* __restrict__ inputs,
    const float* __restrict__ att_w, const float* __restrict__ att_gamma,
    const float* __restrict__ att_beta, const float* __restrict__ att_mean,
    const float* __restrict__ att_var,
    const float* __restrict__ proj_w,
    const float* __restrict__ glu_w, const float* __restrict__ glu_gamma,
    const float* __restrict__ glu_beta, const float* __restrict__ glu_mean,
    const float* __restrict__ glu_var,
    const float* __restrict__ out_w,
    f16* __restrict__ inputs16,
    f16* __restrict__ watt, f16* __restrict__ wproj, f16* __restrict__ wglu,
    f16* __restrict__ wout, float* __restrict__ t_att, float* __restrict__ t_glu)
{
    int tid = blockIdx.x * blockDim.x + threadIdx.x;
    int nth = gridDim.x * blockDim.x;
    for (int i = tid; i < 65536 * 512 / 8; i += nth) {
        float4 u0 = ((const float4*)inputs)[i * 2];
        float4 u1 = ((const float4*)inputs)[i * 2 + 1];
        f16x8 h = {(f16)u0.x, (f16)u0.y, (f16)u0.z, (f16)u0.w,
                   (f16)u1.x, (f16)u1.y, (f16)u1.z, (f16)u1.w};
        ((f16x8*)inputs16)[i] = h;
    }
    for (int i = tid; i < 512 * 512; i += nth) {
        int n = i >> 9, k = i & 511;
        float s = att_gamma[n] * rsqrtf(att_var[n] + EPSBN);
        watt[i] = (f16)(att_w[k * 512 + n] * s);
    }
    for (int i = tid; i < 256 * 512; i += nth) {
        int n = i >> 9, k = i & 511;
        wproj[i] = (f16)(proj_w[k * 256 + n]);
    }
    for (int i = tid; i < 4 * 512 * 256; i += nth) {
        int g = i >> 17, r = i & 131071;
        int n = r >> 8, k = r & 255;
        int c = (n & 1) ? 256 + (n >> 1) : (n >> 1);
        float s = glu_gamma[g * 512 + c] * rsqrtf(glu_var[g * 512 + c] + EPSBN);
        wglu[i] = (f16)(glu_w[g * 131072 + k * 512 + c] * s);
    }
    for (int i = tid; i < 128 * 256; i += nth) {
        int n = i >> 8, k = i & 255;
        wout[i] = (f16)(out_w[k * 128 + n]);
    }
    for (int n = tid; n < 512; n += nth) {
        float s = att_gamma[n] * rsqrtf(att_var[n] + EPSBN);
        t_att[n] = att_beta[n] - att_mean[n] * s;
    }
    for (int i = tid; i < 4 * 512; i += nth) {
        int g = i >> 9, n = i & 511;
        int c = (n & 1) ? 256 + (n >> 1) : (n >> 1);
        float s = glu_gamma[g * 512 + c] * rsqrtf(glu_var[g * 512 + c] + EPSBN);
        t_glu[i] = glu_beta[g * 512 + c] - glu_mean[g * 512 + c] * s;
    }
}

// ---------------- fused att GEMM + register sparsemax ----------------
// 256 threads / 4 waves; block tile 64 rows x 512 cols; wave w: rows w*16..+16, all cols.
// acc[n][j]: row = w*16 + lq*4 + j, col = n*16 + lr. Row r lives on 16 lanes lq=const.
__global__ __launch_bounds__(256, 2) void att_sparsemax_kernel(
    const f16* __restrict__ in16, const f16* __restrict__ watt,
    const float* __restrict__ t_att, const float* __restrict__ priors,
    float* __restrict__ maskout, float* __restrict__ npout,
    f16* __restrict__ masked)
{
    __shared__ f16 lds[64 * 520];  // 66.5KB: [0,2048)=A, [2048,18432)=B; reused as M[64][520]
    f16* Alds = lds;
    f16* Blds = lds + 2048;
    const int rBase = blockIdx.x * 64;
    const int tid = threadIdx.x;
    const int lane = tid & 63;
    const int w = tid >> 6;
    const int lr = lane & 15, lq = lane >> 4;

    f32x4 acc[32];
#pragma unroll
    for (int n = 0; n < 32; n++) acc[n] = (f32x4){0.f, 0.f, 0.f, 0.f};

    for (int k0 = 0; k0 < 512; k0 += 32) {
        __syncthreads();  // previous step's ds_reads done
        {   // A tile 64x32 f16 = 256 chunks of 16B; chunk c: row=c>>2, kc=c&3
            const int c = w * 64 + lane;
            stage16(in16 + (size_t)(rBase + (c >> 2)) * 512 + k0 + (c & 3) * 8,
                    Alds + w * 512);
        }
#pragma unroll
        for (int i = 0; i < 8; i++) {  // B tile 512x32 f16 = 2048 chunks, 32 wave-issues
            const int g = w * 8 + i;
            const int c = g * 64 + lane;
            stage16(watt + (size_t)(c >> 2) * 512 + k0 + (c & 3) * 8,
                    Blds + g * 512);
        }
        __syncthreads();  // staging complete
        f16x8 af = *(const f16x8*)&Alds[(w * 16 + lr) * 32 + lq * 8];
#pragma unroll
        for (int n = 0; n < 32; n++) {
            f16x8 bf = *(const f16x8*)&Blds[(n * 16 + lr) * 32 + lq * 8];
            acc[n] = __builtin_amdgcn_mfma_f32_16x16x32_f16(af, bf, acc[n], 0, 0, 0);
        }
    }
    __syncthreads();  // all waves' LDS reads done; lds reusable as M

    // phase 1: z = (acc + t) * priors, f32 in regs
#pragma unroll
    for (int n = 0; n < 32; n++) {
        const float t = t_att[n * 16 + lr];
        const size_t pb = (size_t)(rBase + w * 16 + lq * 4) * 512 + n * 16 + lr;
#pragma unroll
        for (int j = 0; j < 4; j++)
            acc[n][j] = (acc[n][j] + t) * priors[pb + (size_t)j * 512];
    }

    // phase 2: per-row sparsemax over 16-lane groups (4 rows per group via j)
    float lo[4], hi[4];
#pragma unroll
    for (int j = 0; j < 4; j++) {
        float m = acc[0][j];
#pragma unroll
        for (int n = 1; n < 32; n++) m = fmaxf(m, acc[n][j]);
#pragma unroll
        for (int d = 1; d < 16; d <<= 1) m = fmaxf(m, __shfl_xor(m, d, 64));
        lo[j] = m - 1.f; hi[j] = m;
    }
    for (int it = 0; it < 10; ++it) {
#pragma unroll
        for (int j = 0; j < 4; j++) {
            const float tau = 0.5f * (lo[j] + hi[j]);
            float s = 0.f;
#pragma unroll
            for (int n = 0; n < 32; n++) s += fmaxf(acc[n][j] - tau, 0.f);
#pragma unroll
            for (int d = 1; d < 16; d <<= 1) s += __shfl_xor(s, d, 64);
            if (s >= 1.f) lo[j] = tau; else hi[j] = tau;
        }
    }
    float tau[4];
#pragma unroll
    for (int j = 0; j < 4; j++) {
        float cnt = 0.f, sm = 0.f;
#pragma unroll
        for (int n = 0; n < 32; n++) {
            if (acc[n][j] > lo[j]) { cnt += 1.f; sm += acc[n][j]; }
        }
#pragma unroll
        for (int d = 1; d < 16; d <<= 1) {
            cnt += __shfl_xor(cnt, d, 64);
            sm += __shfl_xor(sm, d, 64);
        }
        tau[j] = (sm - 1.f) / cnt;
    }

    // phase 3: mask into acc; write mask, np (16-lane x f32 = full 64B sectors)
#pragma unroll
    for (int n = 0; n < 32; n++) {
        const size_t pb = (size_t)(rBase + w * 16 + lq * 4) * 512 + n * 16 + lr;
#pragma unroll
        for (int j = 0; j < 4; j++) {
            const float mk = fmaxf(acc[n][j] - tau[j], 0.f);
            acc[n][j] = mk;
            maskout[pb + (size_t)j * 512] = mk;
            npout[pb + (size_t)j * 512] = priors[pb + (size_t)j * 512] * (1.f - mk);
        }
    }

    // phase 4: masked = mask * inputs, coalesced via LDS repack
#pragma unroll
    for (int n = 0; n < 32; n++)
#pragma unroll
        for (int j = 0; j < 4; j++)
            lds[(w * 16 + lq * 4 + j) * 520 + n * 16 + lr] = (f16)acc[n][j];
    __syncthreads();
#pragma unroll
    for (int i = 0; i < 16; i++) {
        const int c = i * 256 + tid;
        const int row = c >> 6, col8 = (c & 63) * 8;
        f16x8 mv = *(const f16x8*)&lds[row * 520 + col8];
        f16x8 xv = *(const f16x8*)(in16 + (size_t)(rBase + row) * 512 + col8);
        *(f16x8*)(masked + (size_t)(rBase + row) * 512 + col8) = mv * xv;
    }
}

// ---------------- m97-style 128x128 MFMA GEMM (round-3 proven) ----------------
template <int K, int NBLK, int EPI>
__global__ __launch_bounds__(256) void gemm_kernel(
    const f16* __restrict__ A, const f16* __restrict__ Bt,
    const float* __restrict__ tb, const f16* __restrict__ xold,
    float* __restrict__ outF, f16* __restrict__ outH)
{
    __shared__ f16 Alds[128 * 32];
    __shared__ f16 Blds[128 * 32];
    int wg = blockIdx.x;
    const int chunk = gridDim.x >> 3;
    wg = (wg & 7) * chunk + (wg >> 3);
    const int rBase = (wg / NBLK) * 128;
    const int cBase = (wg % NBLK) * 128;
    const int tid = threadIdx.x;
    const int lane = tid & 63;
    const int w = tid >> 6;
    const int wr = w & 1, wc = w >> 1;
    const int lr = lane & 15, lq = lane >> 4;

    f32x4 acc[4][4];
#pragma unroll
    for (int m = 0; m < 4; m++)
#pragma unroll
        for (int n = 0; n < 4; n++) acc[m][n] = (f32x4){0.f, 0.f, 0.f, 0.f};

    for (int k0 = 0; k0 < K; k0 += 32) {
        __syncthreads();
#pragma unroll
        for (int i = 0; i < 2; i++) {
            const int c = i * 256 + tid;  // chunk over [128][32]: row=c>>2, kc=c&3
            stage16(A + (size_t)(rBase + (c >> 2)) * K + k0 + (c & 3) * 8,
                    (const f16*)((const char*)Alds + (i * 256 + (w << 6)) * 16));
            stage16(Bt + (size_t)(cBase + (c >> 2)) * K + k0 + (c & 3) * 8,
                    (const f16*)((const char*)Blds + (i * 256 + (w << 6)) * 16));
        }
        __syncthreads();
        f16x8 af[4], bf[4];
#pragma unroll
        for (int m = 0; m < 4; m++)
            af[m] = *(const f16x8*)&Alds[(wr * 64 + m * 16 + lr) * 32 + lq * 8];
#pragma unroll
        for (int n = 0; n < 4; n++)
            bf[n] = *(const f16x8*)&Blds[(wc * 64 + n * 16 + lr) * 32 + lq * 8];
#pragma unroll
        for (int m = 0; m < 4; m++)
#pragma unroll
            for (int n = 0; n < 4; n++)
                acc[m][n] = __builtin_amdgcn_mfma_f32_16x16x32_f16(af[m], bf[n], acc[m][n], 0, 0, 0);
    }

#pragma unroll
    for (int m = 0; m < 4; m++) {
#pragma unroll
        for (int n = 0; n < 4; n++) {
            const int Rb = rBase + wr * 64 + m * 16 + lq * 4;
            const int Cc = cBase + wc * 64 + n * 16 + lr;
#pragma unroll
            for (int j = 0; j < 4; j++) {
                const int R = Rb + j;
                float v = acc[m][n][j] + tb[Cc];
                if constexpr (EPI == EPI_PROJ) {
                    outH[(size_t)R * 256 + Cc] = (f16)v;
                } else if constexpr (EPI == EPI_GLU) {
                    float o = __shfl_xor(v, 1, 64);  // val<->gate (interleaved cols)
                    if (!(lane & 1)) {
                        const int xi = Cc >> 1;
                        const size_t id = (size_t)R * 256 + xi;
                        float xn = v * (1.f / (1.f + __expf(-o)));
                        outH[id] = (f16)(xn + (float)xold[id]);
                    }
                } else {  // EPI_OUT
                    outF[(size_t)R * 128 + Cc] = v;
                }
            }
        }
    }
}

extern "C" void kernel_launch(void* const* d_in, const int* in_sizes, int n_in,
                              void* d_out, int out_size, void* d_ws, size_t ws_size,
                              hipStream_t stream)
{
    const float* inputs    = (const float*)d_in[0];
    const float* priors    = (const float*)d_in[1];
    const float* att_w     = (const float*)d_in[2];
    const float* att_gamma = (const float*)d_in[3];
    const float* att_beta  = (const float*)d_in[4];
    const float* att_mean  = (const float*)d_in[5];
    const float* att_var   = (const float*)d_in[6];
    const float* proj_w    = (const float*)d_in[7];
    const float* proj_b    = (const float*)d_in[8];
    const float* glu_w     = (const float*)d_in[9];
    const float* glu_gamma = (const float*)d_in[10];
    const float* glu_beta  = (const float*)d_in[11];
    const float* glu_mean  = (const float*)d_in[12];
    const float* glu_var   = (const float*)d_in[13];
    const float* out_w     = (const float*)d_in[14];
    const float* out_b     = (const float*)d_in[15];

    char* ws = (char*)d_ws;
    f16*   watt     = (f16*)(ws + 0);          // 512*512 f16
    f16*   wproj    = (f16*)(ws + 524288);     // 256*512
    f16*   wglu     = (f16*)(ws + 786432);     // 4*512*256
    f16*   wout     = (f16*)(ws + 1835008);    // 128*256
    float* t_att    = (float*)(ws + 1900544);  // 512
    float* t_glu    = (float*)(ws + 1902592);  // 4*512
    f16*   inputs16 = (f16*)(ws + 2097152);    // 65536*512 f16 (64MB)
    f16*   maskedb  = (f16*)(ws + 69206016);   // 65536*512 f16
    f16*   x0       = (f16*)(ws + 136314880);  // 65536*256 f16
    f16*   x1       = (f16*)(ws + 169869312);  // 65536*256 f16

    float* outp  = (float*)d_out;
    float* maskp = outp + (size_t)65536 * 128;
    float* npp   = maskp + (size_t)65536 * 512;

    prep_kernel<<<2048, 256, 0, stream>>>(inputs, att_w, att_gamma, att_beta, att_mean,
                                          att_var, proj_w, glu_w, glu_gamma, glu_beta,
                                          glu_mean, glu_var, out_w, inputs16,
                                          watt, wproj, wglu, wout, t_att, t_glu);

    att_sparsemax_kernel<<<1024, 256, 0, stream>>>(
        inputs16, watt, t_att, priors, maskp, npp, maskedb);

    gemm_kernel<512, 2, EPI_PROJ><<<1024, 256, 0, stream>>>(
        maskedb, wproj, proj_b, nullptr, nullptr, x0);

    gemm_kernel<256, 4, EPI_GLU><<<2048, 256, 0, stream>>>(
        x0, wglu, t_glu, x0, nullptr, x1);
    gemm_kernel<256, 4, EPI_GLU><<<2048, 256, 0, stream>>>(
        x1, wglu + 131072, t_glu + 512, x1, nullptr, x0);
    gemm_kernel<256, 4, EPI_GLU><<<2048, 256, 0, stream>>>(
        x0, wglu + 262144, t_glu + 1024, x0, nullptr, x1);
    gemm_kernel<256, 4, EPI_GLU><<<2048, 256, 0, stream>>>(
        x1, wglu + 393216, t_glu + 1536, x1, nullptr, x0);

    gemm_kernel<256, 1, EPI_OUT><<<512, 256, 0, stream>>>(
        x0, wout, out_b, nullptr, outp, nullptr);
}